// Round 6
// baseline (532.693 us; speedup 1.0000x reference)
//
#include <hip/hip_runtime.h>
#include <hip/hip_fp16.h>

// Fixed problem shape
#define TOK   64
#define INF   4096
#define OUTF  11008
#define NSLC  (OUTF * INF / 64)   // 704512 64-element slices
#define NBLK  (OUTF / 16)         // 688 GEMM blocks

// Harness dtypes: fp16 arrays arrive as fp32; ints as int32; output fp32.
typedef __attribute__((ext_vector_type(8))) _Float16 half8;
typedef __attribute__((ext_vector_type(4))) _Float16 half4;
typedef __attribute__((ext_vector_type(4))) float floatx4;

// ---------------------------------------------------------------------------
// Precompute: (a) x fp32 -> fp16 (512 KB, L2-resident A for the GEMM),
// (b) cum64[s] = lower_bound(fp16_pos, s*64) for all 704513 slice boundaries
//     (2.8 MB, L2-resident). 704513 INDEPENDENT binary searches — latency
//     fully overlapped across ~11k waves.
// With cum64, the compacted-stream index of any non-outlier position p is
// p - cum64[p>>6] - (#outliers in [p & ~63, p)), the last term resolvable by
// scanning cum64[s+1]-cum64[s] entries (avg 0.17, usually 0).
// ---------------------------------------------------------------------------
__global__ __launch_bounds__(256) void precompute_kernel(
    const float* __restrict__ x, const int* __restrict__ fppos, int nf,
    _Float16* __restrict__ x16, int* __restrict__ cum64) {
  const int t = blockIdx.x * 256 + threadIdx.x;
  if (t < (TOK * INF) / 4) {
    const floatx4 f = *(const floatx4*)&x[t * 4];
    half4 h;
    h[0] = (_Float16)f[0]; h[1] = (_Float16)f[1];
    h[2] = (_Float16)f[2]; h[3] = (_Float16)f[3];
    *(half4*)&x16[t * 4] = h;
  }
  if (t <= NSLC) {
    const int target = t << 6;
    int lo = 0, hi = nf;  // first index with fppos[idx] >= target
    while (lo < hi) {
      const int mid = (lo + hi) >> 1;
      if (fppos[mid] < target) lo = mid + 1; else hi = mid;
    }
    cum64[t] = lo;
  }
}

// ---------------------------------------------------------------------------
// Fused dequant+GEMM: out = x @ W^T + bias with W never materialized.
// R5's barrier-free structure: block = 16 output rows [n0,n0+16), 4 waves =
// K-quarters (1024 = one quant block per row -> scale is loop-invariant per
// lane). Wave does full M=64 as 4 MFMA tiles per K=32 step; one LDS
// cross-wave reduction at the end.
// B-fragments are dequantized IN REGISTERS: lane (row=ln, k=quad*8) loads its
// 8-run's compacted int8 values as one 32 B vector load at i0 derived from
// cum64 (no dependent-scan chain — R3's failure mode). Outlier-carrying runs
// (prob ~0.17/slice) take a rare per-element path.
// mfma_f32_16x16x32_f16: A/B frag idx=lane&15, k=quad*8+j; D row=quad*4+i,
// col=lane&15  [verified rounds 2-5].
// ---------------------------------------------------------------------------
__global__ __launch_bounds__(256) void fused_gemm_kernel(
    const _Float16* __restrict__ x16, const int* __restrict__ i8,
    const float* __restrict__ fpdat, const int* __restrict__ fppos,
    const float* __restrict__ scales, const float* __restrict__ bias,
    const int* __restrict__ cum64, float* __restrict__ out, int n8) {
  __shared__ float red[4 * 64 * 16];  // [wave][m][n] partials, 16 KB

  const int tid  = threadIdx.x;
  const int wave = tid >> 6;
  const int lane = tid & 63;
  const int quad = lane >> 4;
  const int ln   = lane & 15;
  const int n0   = blockIdx.x * 16;

  const int r = n0 + ln;                       // W row this lane dequants
  const float s = scales[r * 4 + wave];        // loop-invariant quant scale
  const int pbase = r * INF + wave * 1024 + quad * 8;

  const _Float16* ap = &x16[ln * INF + wave * 1024 + quad * 8];

  floatx4 acc0 = {0,0,0,0}, acc1 = {0,0,0,0}, acc2 = {0,0,0,0}, acc3 = {0,0,0,0};

#pragma unroll 2
  for (int st = 0; st < 32; ++st) {
    const int p  = pbase + st * 32;   // flat W position of this lane's 8-run
    const int sI = p >> 6;
    const int c0 = cum64[sI];
    const int c1 = cum64[sI + 1];

    // Outliers in this 64-slice (avg 0.17): count those below p, flag in-run.
    int f = 0, lt = 0;
    for (int j = c0; j < c1; ++j) {
      const int d = fppos[j] - p;
      lt += (d < 0);
      f |= ((unsigned)d < 8u) ? (1 << d) : 0;
    }

    const int i0 = p - c0 - lt;  // compacted index of position p
    half8 bh;
    if ((f == 0) & (i0 + 8 <= n8)) {
      // Fast path: 8 consecutive compacted int32 values, one 32 B load.
      int l[8];
      __builtin_memcpy(l, &i8[i0], 32);
#pragma unroll
      for (int e = 0; e < 8; ++e) bh[e] = (_Float16)((float)l[e] * s);
    } else {
      // Rare path: walk compacted stream / in-run outliers element-wise.
      int q = i0, jo = c0 + lt;
      const int m = n8 - 1;
#pragma unroll
      for (int e = 0; e < 8; ++e) {
        const int flg = (f >> e) & 1;
        float v;
        if (flg) { v = fpdat[jo]; ++jo; }
        else     { v = (float)i8[q > m ? m : q] * s; ++q; }
        bh[e] = (_Float16)v;
      }
    }

    // A-fragments (L2-resident x16) + 4 MFMA tiles (M = 64).
    const int ko = st * 32;
    const half8 a0 = *(const half8*)&ap[ko];
    const half8 a1 = *(const half8*)&ap[16 * INF + ko];
    const half8 a2 = *(const half8*)&ap[32 * INF + ko];
    const half8 a3 = *(const half8*)&ap[48 * INF + ko];
    acc0 = __builtin_amdgcn_mfma_f32_16x16x32_f16(a0, bh, acc0, 0, 0, 0);
    acc1 = __builtin_amdgcn_mfma_f32_16x16x32_f16(a1, bh, acc1, 0, 0, 0);
    acc2 = __builtin_amdgcn_mfma_f32_16x16x32_f16(a2, bh, acc2, 0, 0, 0);
    acc3 = __builtin_amdgcn_mfma_f32_16x16x32_f16(a3, bh, acc3, 0, 0, 0);
  }

  // Cross-wave K-reduction. Lane holds C[t*16 + quad*4 + i][ln] for tile t.
  const int mb = quad * 4;
#pragma unroll
  for (int i = 0; i < 4; ++i) red[wave * 1024 + (mb + i)      * 16 + ln] = acc0[i];
#pragma unroll
  for (int i = 0; i < 4; ++i) red[wave * 1024 + (16 + mb + i) * 16 + ln] = acc1[i];
#pragma unroll
  for (int i = 0; i < 4; ++i) red[wave * 1024 + (32 + mb + i) * 16 + ln] = acc2[i];
#pragma unroll
  for (int i = 0; i < 4; ++i) red[wave * 1024 + (48 + mb + i) * 16 + ln] = acc3[i];
  __syncthreads();

#pragma unroll
  for (int c2 = 0; c2 < 4; ++c2) {
    const int cell = tid + c2 * 256;  // 1024 cells = 64 m x 16 n
    const int mm = cell >> 4, nn = cell & 15;
    const float v = red[cell] + red[1024 + cell] + red[2048 + cell] +
                    red[3072 + cell] + bias[n0 + nn];
    out[mm * OUTF + n0 + nn] = v;
  }
}

// ---------------------------------------------------------------------------
// Inputs: 0 x(fp32) 1 int8_data(i32) 2 fp16_data(fp32) 3 scales(fp32)
// 4 bias(fp32) 5 int8_pos(UNUSED) 6 fp16_pos(i32) 7 block_idx(UNUSED)
// ws: x16 (512 KB) | cum64 (int[704513], 2.82 MB). No W materialization.
// ---------------------------------------------------------------------------
extern "C" void kernel_launch(void* const* d_in, const int* in_sizes, int n_in,
                              void* d_out, int out_size, void* d_ws,
                              size_t ws_size, hipStream_t stream) {
  const float* x      = (const float*)d_in[0];
  const int*   i8     = (const int*)d_in[1];
  const float* fpdat  = (const float*)d_in[2];
  const float* scales = (const float*)d_in[3];
  const float* bias   = (const float*)d_in[4];
  const int*   fppos  = (const int*)d_in[6];

  char* wsp = (char*)d_ws;
  _Float16* x16   = (_Float16*)wsp;
  int*      cum64 = (int*)(wsp + (size_t)TOK * INF * sizeof(_Float16));
  float*    out   = (float*)d_out;

  const int n8 = in_sizes[1];
  const int nf = in_sizes[2];

  precompute_kernel<<<(NSLC + 256) / 256 + 1, 256, 0, stream>>>(x, fppos, nf,
                                                                x16, cum64);
  fused_gemm_kernel<<<NBLK, 256, 0, stream>>>(x16, i8, fpdat, fppos, scales,
                                              bias, cum64, out, n8);
}

// Round 7
// 488.942 us; speedup vs baseline: 1.0895x; 1.0895x over previous
//
#include <hip/hip_runtime.h>
#include <hip/hip_fp16.h>

// Fixed problem shape
#define TOK   64
#define INF   4096
#define OUTF  11008
#define NSLC  (OUTF * INF / 64)   // 704512 64-element slices
#define NBLK  (OUTF / 16)         // 688 N-tiles
#define KSPL  4                   // K-split across blocks -> 2752 blocks

// Harness dtypes: fp16 arrays arrive as fp32; ints as int32; output fp32.
typedef __attribute__((ext_vector_type(8))) _Float16 half8;
typedef __attribute__((ext_vector_type(4))) _Float16 half4;
typedef __attribute__((ext_vector_type(4))) float floatx4;

// ---------------------------------------------------------------------------
// Precompute: (a) x fp32 -> fp16 (512 KB, L2-resident A for the GEMM),
// (b) cum64[s] = lower_bound(fp16_pos, s*64) for all 704513 slice boundaries
//     (2.8 MB, L2-resident) — independent searches, latency overlapped.
// Compacted index of non-outlier p: p - cum64[p>>6] - (#outliers in [p&~63,p)).
// ---------------------------------------------------------------------------
__global__ __launch_bounds__(256) void precompute_kernel(
    const float* __restrict__ x, const int* __restrict__ fppos, int nf,
    _Float16* __restrict__ x16, int* __restrict__ cum64) {
  const int t = blockIdx.x * 256 + threadIdx.x;
  if (t < (TOK * INF) / 4) {
    const floatx4 f = *(const floatx4*)&x[t * 4];
    half4 h;
    h[0] = (_Float16)f[0]; h[1] = (_Float16)f[1];
    h[2] = (_Float16)f[2]; h[3] = (_Float16)f[3];
    *(half4*)&x16[t * 4] = h;
  }
  if (t <= NSLC) {
    const int target = t << 6;
    int lo = 0, hi = nf;
    while (lo < hi) {
      const int mid = (lo + hi) >> 1;
      if (fppos[mid] < target) lo = mid + 1; else hi = mid;
    }
    cum64[t] = lo;
  }
}

// ---------------------------------------------------------------------------
// Fused dequant+GEMM, K-split. Block = (n-tile, K-quarter): nt = bid>>2 owns
// rows [nt*16, nt*16+16), kq = bid&3 owns K in [kq*1024, +1024) — one quant
// block per lane-row -> loop-invariant scale. Wave w takes the 256-K slice
// [kq*1024 + w*256, +256) = 8 steps of K=32; full M=64 as 4 MFMA tiles.
// 2752 blocks -> occupancy at the 32-wave/CU cap (R6 was 10.75 waves/CU,
// latency-bound at 28%). Partials: LDS reduce across the 4 waves, then one
// global atomicAdd per cell; kq==0 blocks fold in bias; out pre-zeroed by
// hipMemsetAsync.
// mfma_f32_16x16x32_f16: A/B frag idx=lane&15, k=quad*8+j; D row=quad*4+i,
// col=lane&15  [verified rounds 2-6].
// ---------------------------------------------------------------------------
__global__ __launch_bounds__(256) void fused_gemm_kernel(
    const _Float16* __restrict__ x16, const int* __restrict__ i8,
    const float* __restrict__ fpdat, const int* __restrict__ fppos,
    const float* __restrict__ scales, const float* __restrict__ bias,
    const int* __restrict__ cum64, float* __restrict__ out, int n8) {
  __shared__ float red[4 * 64 * 16];  // [wave][m][n] partials, 16 KB

  const int tid  = threadIdx.x;
  const int wave = tid >> 6;
  const int lane = tid & 63;
  const int quad = lane >> 4;
  const int ln   = lane & 15;
  const int nt   = blockIdx.x >> 2;
  const int kq   = blockIdx.x & 3;
  const int n0   = nt * 16;

  const int r  = n0 + ln;                    // W row this lane dequants
  const float s = scales[r * 4 + kq];        // loop-invariant quant scale
  const int kb = kq * 1024 + wave * 256 + quad * 8;
  const int pbase = r * INF + kb;

  const _Float16* ap = &x16[ln * INF + kb];

  floatx4 acc0 = {0,0,0,0}, acc1 = {0,0,0,0}, acc2 = {0,0,0,0}, acc3 = {0,0,0,0};

  // Hoist all 8 cum64 pairs — independent loads, all in flight at once.
  int c0a[8], c1a[8];
#pragma unroll
  for (int st = 0; st < 8; ++st) {
    const int sI = (pbase + st * 32) >> 6;
    c0a[st] = cum64[sI];
    c1a[st] = cum64[sI + 1];
  }

#pragma unroll
  for (int st = 0; st < 8; ++st) {
    const int p  = pbase + st * 32;
    const int c0 = c0a[st], c1 = c1a[st];

    // Outliers in this 64-slice (avg 0.17): count below p, flag in-run.
    int f = 0, lt = 0;
    for (int j = c0; j < c1; ++j) {
      const int d = fppos[j] - p;
      lt += (d < 0);
      f |= ((unsigned)d < 8u) ? (1 << d) : 0;
    }

    const int i0 = p - c0 - lt;  // compacted index of position p
    half8 bh;
    if ((f == 0) & (i0 + 8 <= n8)) {
      // Fast path: one 32 B load of 8 consecutive compacted int32 values.
      int l[8];
      __builtin_memcpy(l, &i8[i0], 32);
#pragma unroll
      for (int e = 0; e < 8; ++e) bh[e] = (_Float16)((float)l[e] * s);
    } else {
      // Rare path: walk compacted stream / in-run outliers element-wise.
      int q = i0, jo = c0 + lt;
      const int m = n8 - 1;
#pragma unroll
      for (int e = 0; e < 8; ++e) {
        const int flg = (f >> e) & 1;
        float v;
        if (flg) { v = fpdat[jo]; ++jo; }
        else     { v = (float)i8[q > m ? m : q] * s; ++q; }
        bh[e] = (_Float16)v;
      }
    }

    const int ko = st * 32;
    const half8 a0 = *(const half8*)&ap[ko];
    const half8 a1 = *(const half8*)&ap[16 * INF + ko];
    const half8 a2 = *(const half8*)&ap[32 * INF + ko];
    const half8 a3 = *(const half8*)&ap[48 * INF + ko];
    acc0 = __builtin_amdgcn_mfma_f32_16x16x32_f16(a0, bh, acc0, 0, 0, 0);
    acc1 = __builtin_amdgcn_mfma_f32_16x16x32_f16(a1, bh, acc1, 0, 0, 0);
    acc2 = __builtin_amdgcn_mfma_f32_16x16x32_f16(a2, bh, acc2, 0, 0, 0);
    acc3 = __builtin_amdgcn_mfma_f32_16x16x32_f16(a3, bh, acc3, 0, 0, 0);
  }

  // Cross-wave reduction. Lane holds C[t*16 + quad*4 + i][ln] for tile t.
  const int mb = quad * 4;
#pragma unroll
  for (int i = 0; i < 4; ++i) red[wave * 1024 + (mb + i)      * 16 + ln] = acc0[i];
#pragma unroll
  for (int i = 0; i < 4; ++i) red[wave * 1024 + (16 + mb + i) * 16 + ln] = acc1[i];
#pragma unroll
  for (int i = 0; i < 4; ++i) red[wave * 1024 + (32 + mb + i) * 16 + ln] = acc2[i];
#pragma unroll
  for (int i = 0; i < 4; ++i) red[wave * 1024 + (48 + mb + i) * 16 + ln] = acc3[i];
  __syncthreads();

#pragma unroll
  for (int c2 = 0; c2 < 4; ++c2) {
    const int cell = tid + c2 * 256;  // 1024 cells = 64 m x 16 n
    const int mm = cell >> 4, nn = cell & 15;
    float v = red[cell] + red[1024 + cell] + red[2048 + cell] + red[3072 + cell];
    if (kq == 0) v += bias[n0 + nn];
    atomicAdd(&out[mm * OUTF + n0 + nn], v);
  }
}

// ---------------------------------------------------------------------------
// Inputs: 0 x(fp32) 1 int8_data(i32) 2 fp16_data(fp32) 3 scales(fp32)
// 4 bias(fp32) 5 int8_pos(UNUSED) 6 fp16_pos(i32) 7 block_idx(UNUSED)
// ws: x16 (512 KB) | cum64 (int[704513], 2.82 MB). No W materialization.
// ---------------------------------------------------------------------------
extern "C" void kernel_launch(void* const* d_in, const int* in_sizes, int n_in,
                              void* d_out, int out_size, void* d_ws,
                              size_t ws_size, hipStream_t stream) {
  const float* x      = (const float*)d_in[0];
  const int*   i8     = (const int*)d_in[1];
  const float* fpdat  = (const float*)d_in[2];
  const float* scales = (const float*)d_in[3];
  const float* bias   = (const float*)d_in[4];
  const int*   fppos  = (const int*)d_in[6];

  char* wsp = (char*)d_ws;
  _Float16* x16   = (_Float16*)wsp;
  int*      cum64 = (int*)(wsp + (size_t)TOK * INF * sizeof(_Float16));
  float*    out   = (float*)d_out;

  const int n8 = in_sizes[1];
  const int nf = in_sizes[2];

  hipMemsetAsync(out, 0, (size_t)out_size * sizeof(float), stream);
  precompute_kernel<<<(NSLC + 256) / 256 + 1, 256, 0, stream>>>(x, fppos, nf,
                                                                x16, cum64);
  fused_gemm_kernel<<<NBLK * KSPL, 256, 0, stream>>>(x16, i8, fpdat, fppos,
                                                     scales, bias, cum64, out,
                                                     n8);
}

// Round 8
// 486.520 us; speedup vs baseline: 1.0949x; 1.0050x over previous
//
#include <hip/hip_runtime.h>
#include <hip/hip_fp16.h>

// Fixed problem shape
#define TOK   64
#define INF   4096
#define OUTF  11008
#define NQB   44032             // numel/1024 quant blocks
#define NBLK  (OUTF / 16)       // 688 N-tiles
#define KSPL  4                 // K-split -> 2752 blocks
#define BPAD  1032              // B-tile K stride in halves (+8 pad, keeps 16B align)
#define MAXO  24                // per-(row,kq) outlier cache cap (mean 2.76, P(>24)~1e-11)

// Harness dtypes: fp16 arrays arrive as fp32; ints as int32; output fp32.
typedef __attribute__((ext_vector_type(8))) _Float16 half8;
typedef __attribute__((ext_vector_type(4))) _Float16 half4;
typedef __attribute__((ext_vector_type(4))) float floatx4;

// ---------------------------------------------------------------------------
// Precompute: (a) x fp32 -> fp16 (512 KB, L2-resident A), (b) cum[b] =
// lower_bound(fp16_pos, b*1024) for the 44033 quant-block boundaries —
// independent binary searches, latency overlapped (R5-verified, ~3 us).
// ---------------------------------------------------------------------------
__global__ __launch_bounds__(256) void precompute_kernel(
    const float* __restrict__ x, const int* __restrict__ fppos, int nf,
    _Float16* __restrict__ x16, int* __restrict__ cum) {
  const int t = blockIdx.x * 256 + threadIdx.x;
  if (t < (TOK * INF) / 4) {
    const floatx4 f = *(const floatx4*)&x[t * 4];
    half4 h;
    h[0] = (_Float16)f[0]; h[1] = (_Float16)f[1];
    h[2] = (_Float16)f[2]; h[3] = (_Float16)f[3];
    *(half4*)&x16[t * 4] = h;
  }
  if (t <= NQB) {
    const int target = t << 10;
    int lo = 0, hi = nf;
    while (lo < hi) {
      const int mid = (lo + hi) >> 1;
      if (fppos[mid] < target) lo = mid + 1; else hi = mid;
    }
    cum[t] = lo;
  }
}

// ---------------------------------------------------------------------------
// Fused dequant+GEMM with bulk LDS staging (NOT per-lane gathers — R6/R7's
// latency wall). Block = (nt, kq): rows [nt*16,+16), K [kq*1024,+1024).
//
// Phase A: each row's non-outliers are one CONTIGUOUS compacted i8 range
// starting at c_lo = pos0 - cum[b]. 16 loaders/row stream it via aligned
// int4 loads (aligned-down base, slot = idx - off); dequantized fp16 values
// scatter into LDS B-tile [row][k] where k = slot + shift(slot),
// shift(t) = #{ key_i <= t }, key_i = (outlier local pos) - rank. Outliers
// patched directly. All load addresses known up front -> full MLP.
//
// Phase B: mfma_f32_16x16x32_f16 (A/B frag idx=lane&15, k=quad*8+j;
// D row=quad*4+i, col=lane&15 — verified R2-R7). B-frag via ds_read_b128,
// A from L2-resident x16. Wave = 256-K slice, 8 steps, full M=64 (4 tiles).
// Epilogue: LDS (aliased over B-tile) cross-wave reduce + atomicAdd;
// kq==0 folds bias; out pre-zeroed by hipMemsetAsync.
// ---------------------------------------------------------------------------
__global__ __launch_bounds__(256) void fused_kernel(
    const _Float16* __restrict__ x16, const int* __restrict__ i8,
    const float* __restrict__ fpdat, const int* __restrict__ fppos,
    const float* __restrict__ scales, const float* __restrict__ bias,
    const int* __restrict__ cum, float* __restrict__ out, int n8) {
  __shared__ __align__(16) _Float16 Bs[16 * BPAD];   // 33 KB, aliased by red[]
  __shared__ int   key_sh[16][MAXO];
  __shared__ float oval_sh[16][MAXO];

  const int tid = threadIdx.x;
  const int nt  = blockIdx.x >> 2;
  const int kq  = blockIdx.x & 3;
  const int n0  = nt * 16;

  // ---- Phase A: stage + dequant the 16 x 1024 B-tile ----
  const int rr = tid >> 4;          // row in tile
  const int jj = tid & 15;          // loader within row
  const int r  = n0 + rr;
  const int b  = r * 4 + kq;
  const int T0 = cum[b], T1 = cum[b + 1];
  const int nbout = T1 - T0;
  const int nbo   = nbout < MAXO ? nbout : MAXO;
  const int pos0  = r * INF + kq * 1024;
  const int c_lo  = pos0 - T0;      // compacted start of this row's range
  const int nint  = 1024 - nbout;   // valid compacted count
  const float s   = scales[b];

  if (jj == 0) {
    for (int i = 0; i < nbo; ++i) {
      const int o = fppos[T0 + i] - pos0;   // local outlier pos in [0,1024)
      key_sh[rr][i] = o - i;
      oval_sh[rr][i] = fpdat[T0 + i];
    }
  }
  __syncthreads();

  const int off  = c_lo & 3;
  const int c_al = c_lo - off;      // 16 B-aligned int index
#pragma unroll
  for (int it = 0; it < 16; ++it) {
    const int gi = c_al + 4 * (jj + 16 * it);
    const int t0 = 4 * (jj + 16 * it) - off;
    int l[4];
    if (gi + 3 < n8) {
      __builtin_memcpy(l, &i8[gi], 16);
    } else {  // only the very tail of i8 (last row of last block)
#pragma unroll
      for (int e = 0; e < 4; ++e) {
        int idx = gi + e; if (idx > n8 - 1) idx = n8 - 1;
        l[e] = i8[idx];
      }
    }
#pragma unroll
    for (int e = 0; e < 4; ++e) {
      const int t = t0 + e;
      if ((unsigned)t < (unsigned)nint) {
        int sft = 0;
        for (int i = 0; i < nbo; ++i) sft += (key_sh[rr][i] <= t);
        Bs[rr * BPAD + t + sft] = (_Float16)((float)l[e] * s);
      }
    }
  }
  if (off != 0 && jj == 0) {  // top `off` slots not covered by the main loop
#pragma unroll
    for (int e = 0; e < 4; ++e) {
      const int t = 1024 - off + e;
      if ((unsigned)t < (unsigned)nint) {
        int idx = c_al + 1024 + e; if (idx > n8 - 1) idx = n8 - 1;
        int sft = 0;
        for (int i = 0; i < nbo; ++i) sft += (key_sh[rr][i] <= t);
        Bs[rr * BPAD + t + sft] = (_Float16)((float)i8[idx] * s);
      }
    }
  }
  if (jj == 0) {  // patch outliers
    for (int i = 0; i < nbo; ++i)
      Bs[rr * BPAD + key_sh[rr][i] + i] = (_Float16)oval_sh[rr][i];
  }
  __syncthreads();

  // ---- Phase B: MFMA from LDS ----
  const int wave = tid >> 6;
  const int lane = tid & 63;
  const int quad = lane >> 4;
  const int ln   = lane & 15;
  const int kb   = kq * 1024 + wave * 256 + quad * 8;

  const _Float16* ap = &x16[ln * INF + kb];
  const _Float16* bp = &Bs[ln * BPAD + wave * 256 + quad * 8];

  floatx4 acc0 = {0,0,0,0}, acc1 = {0,0,0,0}, acc2 = {0,0,0,0}, acc3 = {0,0,0,0};
#pragma unroll
  for (int st = 0; st < 8; ++st) {
    const int ko = st * 32;
    const half8 bh = *(const half8*)&bp[ko];
    const half8 a0 = *(const half8*)&ap[ko];
    const half8 a1 = *(const half8*)&ap[16 * INF + ko];
    const half8 a2 = *(const half8*)&ap[32 * INF + ko];
    const half8 a3 = *(const half8*)&ap[48 * INF + ko];
    acc0 = __builtin_amdgcn_mfma_f32_16x16x32_f16(a0, bh, acc0, 0, 0, 0);
    acc1 = __builtin_amdgcn_mfma_f32_16x16x32_f16(a1, bh, acc1, 0, 0, 0);
    acc2 = __builtin_amdgcn_mfma_f32_16x16x32_f16(a2, bh, acc2, 0, 0, 0);
    acc3 = __builtin_amdgcn_mfma_f32_16x16x32_f16(a3, bh, acc3, 0, 0, 0);
  }
  __syncthreads();  // everyone done reading Bs; reuse it as red[]

  float* red = (float*)Bs;  // 16 KB needed, 33 KB available
  const int mb = quad * 4;
#pragma unroll
  for (int i = 0; i < 4; ++i) red[wave * 1024 + (mb + i)      * 16 + ln] = acc0[i];
#pragma unroll
  for (int i = 0; i < 4; ++i) red[wave * 1024 + (16 + mb + i) * 16 + ln] = acc1[i];
#pragma unroll
  for (int i = 0; i < 4; ++i) red[wave * 1024 + (32 + mb + i) * 16 + ln] = acc2[i];
#pragma unroll
  for (int i = 0; i < 4; ++i) red[wave * 1024 + (48 + mb + i) * 16 + ln] = acc3[i];
  __syncthreads();

#pragma unroll
  for (int c2 = 0; c2 < 4; ++c2) {
    const int cell = tid + c2 * 256;  // 1024 cells = 64 m x 16 n
    const int mm = cell >> 4, nn = cell & 15;
    float v = red[cell] + red[1024 + cell] + red[2048 + cell] + red[3072 + cell];
    if (kq == 0) v += bias[n0 + nn];
    atomicAdd(&out[mm * OUTF + n0 + nn], v);
  }
}

// ---------------------------------------------------------------------------
// Inputs: 0 x(fp32) 1 int8_data(i32) 2 fp16_data(fp32) 3 scales(fp32)
// 4 bias(fp32) 5 int8_pos(UNUSED) 6 fp16_pos(i32) 7 block_idx(UNUSED)
// ws: x16 (512 KB) | cum (int[44033]). No W materialization.
// ---------------------------------------------------------------------------
extern "C" void kernel_launch(void* const* d_in, const int* in_sizes, int n_in,
                              void* d_out, int out_size, void* d_ws,
                              size_t ws_size, hipStream_t stream) {
  const float* x      = (const float*)d_in[0];
  const int*   i8     = (const int*)d_in[1];
  const float* fpdat  = (const float*)d_in[2];
  const float* scales = (const float*)d_in[3];
  const float* bias   = (const float*)d_in[4];
  const int*   fppos  = (const int*)d_in[6];

  char* wsp = (char*)d_ws;
  _Float16* x16 = (_Float16*)wsp;
  int*      cum = (int*)(wsp + (size_t)TOK * INF * sizeof(_Float16));
  float*    out = (float*)d_out;

  const int n8 = in_sizes[1];
  const int nf = in_sizes[2];

  hipMemsetAsync(out, 0, (size_t)out_size * sizeof(float), stream);
  precompute_kernel<<<256, 256, 0, stream>>>(x, fppos, nf, x16, cum);
  fused_kernel<<<NBLK * KSPL, 256, 0, stream>>>(x16, i8, fpdat, fppos, scales,
                                                bias, cum, out, n8);
}

// Round 9
// 471.711 us; speedup vs baseline: 1.1293x; 1.0314x over previous
//
#include <hip/hip_runtime.h>
#include <hip/hip_fp16.h>

// Fixed problem shape
#define TOK   64
#define INF   4096
#define OUTF  11008
#define NUMEL (OUTF * INF)        // 45088768
#define NSLC  (NUMEL / 64)        // 704512 64-element slices
#define NQB   (NUMEL / 1024)      // 44032 quant blocks
#define NBLK  (OUTF / 16)         // 688 N-tiles
#define KSPL  4                   // GEMM K-split -> 2752 blocks

// Harness dtypes: fp16 arrays arrive as fp32; ints as int32; output fp32.
typedef __attribute__((ext_vector_type(8))) _Float16 half8;
typedef __attribute__((ext_vector_type(4))) _Float16 half4;
typedef __attribute__((ext_vector_type(4))) float floatx4;
typedef __attribute__((ext_vector_type(4), aligned(4))) int int4u;  // dword-aligned dwordx4

// ---------------------------------------------------------------------------
// Precompute: (a) x fp32 -> fp16 (512 KB, L2-resident GEMM A),
// (b) cum64[s] = lower_bound(fp16_pos, 64*s) for s = 0..NSLC — independent
// binary searches, latency fully overlapped (R5/R6-verified pattern).
// ---------------------------------------------------------------------------
__global__ __launch_bounds__(256) void precompute_kernel(
    const float* __restrict__ x, const int* __restrict__ fppos, int nf,
    _Float16* __restrict__ x16, int* __restrict__ cum64) {
  const int t = blockIdx.x * 256 + threadIdx.x;
  if (t < (TOK * INF) / 4) {
    const floatx4 f = *(const floatx4*)&x[t * 4];
    half4 h;
    h[0] = (_Float16)f[0]; h[1] = (_Float16)f[1];
    h[2] = (_Float16)f[2]; h[3] = (_Float16)f[3];
    *(half4*)&x16[t * 4] = h;
  }
  if (t <= NSLC) {
    const int target = t << 6;
    int lo = 0, hi = nf;
    while (lo < hi) {
      const int mid = (lo + hi) >> 1;
      if (fppos[mid] < target) lo = mid + 1; else hi = mid;
    }
    cum64[t] = lo;
  }
}

// ---------------------------------------------------------------------------
// Dequant v3: thread owns 8 POSITIONED slots [8t, 8t+8) -> single quant scale,
// one aligned half8 (16 B) store. Compacted source start i0 = p0 - cum64 - lt.
// Outlier resolution: 2 predicated probes of the 64-slice window (mean 0.177
// outliers, P(>2)~1e-4 -> rare loop) — NO serialized data-bounded load loop
// (the R4-R8 latency signature). i8 loads: two dword-aligned dwordx4; the
// f!=0 repair path consumes only values already inside those 8 dwords.
// ---------------------------------------------------------------------------
__global__ __launch_bounds__(256) void dequant_kernel(
    const int* __restrict__ i8, const float* __restrict__ fpdat,
    const int* __restrict__ fppos, const float* __restrict__ scales,
    const int* __restrict__ cum64, _Float16* __restrict__ W, int n8) {
  const int t   = blockIdx.x * 256 + threadIdx.x;
  const int p0  = t * 8;
  const int s64 = p0 >> 6;
  const int c0  = cum64[s64];
  const int c1  = cum64[s64 + 1];
  const float s = scales[p0 >> 10];

  int lt = 0, f = 0;
  float ov[8];
#pragma unroll
  for (int e = 0; e < 8; ++e) ov[e] = 0.f;

  const int w = c1 - c0;
  if (w > 0) {  // ~16% of slices; short predicated body, no load loop
    {
      const int d = fppos[c0] - p0;
      const float v = fpdat[c0];
      lt += (d < 0);
      if ((unsigned)d < 8u) {
        f |= 1 << d;
#pragma unroll
        for (int e = 0; e < 8; ++e) ov[e] = (d == e) ? v : ov[e];
      }
    }
    if (w > 1) {
      const int d = fppos[c0 + 1] - p0;
      const float v = fpdat[c0 + 1];
      lt += (d < 0);
      if ((unsigned)d < 8u) {
        f |= 1 << d;
#pragma unroll
        for (int e = 0; e < 8; ++e) ov[e] = (d == e) ? v : ov[e];
      }
    }
    for (int j = 2; j < w; ++j) {  // P ~ 1e-4: correctness-only fallback
      const int d = fppos[c0 + j] - p0;
      const float v = fpdat[c0 + j];
      lt += (d < 0);
      if ((unsigned)d < 8u) {
        f |= 1 << d;
#pragma unroll
        for (int e = 0; e < 8; ++e) ov[e] = (d == e) ? v : ov[e];
      }
    }
  }

  const int i0 = p0 - c0 - lt;  // compacted index of position p0
  half8 oh;
  if (i0 + 8 <= n8) {
    int l[8];
    *(int4u*)&l[0] = *(const int4u*)&i8[i0];      // global_load_dwordx4
    *(int4u*)&l[4] = *(const int4u*)&i8[i0 + 4];  // (dword-aligned OK)
    if (f == 0) {
#pragma unroll
      for (int e = 0; e < 8; ++e) oh[e] = (_Float16)((float)l[e] * s);
    } else {
      // Repair: walk register file l[q], outlier slots take fp values.
      int q = 0;
#pragma unroll
      for (int e = 0; e < 8; ++e) {
        const int flg = (f >> e) & 1;
        int lv = l[0];
#pragma unroll
        for (int qq = 1; qq < 8; ++qq) lv = (q == qq) ? l[qq] : lv;
        oh[e] = flg ? (_Float16)ov[e] : (_Float16)((float)lv * s);
        q += 1 - flg;
      }
    }
  } else {
    // Array-tail path (last couple of waves only): clamped scalar loads.
    int c = 0;
    const int m = n8 - 1;
#pragma unroll
    for (int e = 0; e < 8; ++e) {
      const int flg = (f >> e) & 1;
      int idx = i0 + e - c;
      idx = idx < 0 ? 0 : (idx > m ? m : idx);
      oh[e] = flg ? (_Float16)ov[e] : (_Float16)((float)i8[idx] * s);
      c += flg;
    }
  }
  *(half8*)&W[p0] = oh;
}

// ---------------------------------------------------------------------------
// GEMM v3: out = x @ W^T + bias from materialized W. K-split grid (2752
// blocks -> 32 waves/CU, R7-proven): block = (nt, kq) rows [nt*16,+16),
// K [kq*1024,+1024); wave = 256-K slice, 8 steps; full M=64 as 4 MFMA tiles.
// B = streaming half8 from W (no index chains), A from L2-resident x16.
// LDS cross-wave reduce + one atomicAdd per cell; kq==0 folds bias; out
// zeroed by hipMemsetAsync.
// mfma_f32_16x16x32_f16: A/B frag idx=lane&15, k=quad*8+j; D row=quad*4+i,
// col=lane&15  [verified R2-R8].
// ---------------------------------------------------------------------------
__global__ __launch_bounds__(256) void gemm_kernel(
    const _Float16* __restrict__ x16, const _Float16* __restrict__ W,
    const float* __restrict__ bias, float* __restrict__ out) {
  __shared__ float red[4 * 64 * 16];  // 16 KB

  const int tid  = threadIdx.x;
  const int wave = tid >> 6;
  const int lane = tid & 63;
  const int quad = lane >> 4;
  const int ln   = lane & 15;
  const int nt   = blockIdx.x >> 2;
  const int kq   = blockIdx.x & 3;
  const int n0   = nt * 16;

  const int kb = kq * 1024 + wave * 256 + quad * 8;
  const _Float16* wp = &W[(n0 + ln) * INF + kb];
  const _Float16* ap = &x16[ln * INF + kb];

  floatx4 acc0 = {0,0,0,0}, acc1 = {0,0,0,0}, acc2 = {0,0,0,0}, acc3 = {0,0,0,0};
#pragma unroll
  for (int st = 0; st < 8; ++st) {
    const int ko = st * 32;
    const half8 bh = *(const half8*)&wp[ko];
    const half8 a0 = *(const half8*)&ap[ko];
    const half8 a1 = *(const half8*)&ap[16 * INF + ko];
    const half8 a2 = *(const half8*)&ap[32 * INF + ko];
    const half8 a3 = *(const half8*)&ap[48 * INF + ko];
    acc0 = __builtin_amdgcn_mfma_f32_16x16x32_f16(a0, bh, acc0, 0, 0, 0);
    acc1 = __builtin_amdgcn_mfma_f32_16x16x32_f16(a1, bh, acc1, 0, 0, 0);
    acc2 = __builtin_amdgcn_mfma_f32_16x16x32_f16(a2, bh, acc2, 0, 0, 0);
    acc3 = __builtin_amdgcn_mfma_f32_16x16x32_f16(a3, bh, acc3, 0, 0, 0);
  }

  const int mb = quad * 4;
#pragma unroll
  for (int i = 0; i < 4; ++i) red[wave * 1024 + (mb + i)      * 16 + ln] = acc0[i];
#pragma unroll
  for (int i = 0; i < 4; ++i) red[wave * 1024 + (16 + mb + i) * 16 + ln] = acc1[i];
#pragma unroll
  for (int i = 0; i < 4; ++i) red[wave * 1024 + (32 + mb + i) * 16 + ln] = acc2[i];
#pragma unroll
  for (int i = 0; i < 4; ++i) red[wave * 1024 + (48 + mb + i) * 16 + ln] = acc3[i];
  __syncthreads();

#pragma unroll
  for (int c2 = 0; c2 < 4; ++c2) {
    const int cell = tid + c2 * 256;  // 1024 cells = 64 m x 16 n
    const int mm = cell >> 4, nn = cell & 15;
    float v = red[cell] + red[1024 + cell] + red[2048 + cell] + red[3072 + cell];
    if (kq == 0) v += bias[n0 + nn];
    atomicAdd(&out[mm * OUTF + n0 + nn], v);
  }
}

// ---------------------------------------------------------------------------
// Inputs: 0 x(fp32) 1 int8_data(i32) 2 fp16_data(fp32) 3 scales(fp32)
// 4 bias(fp32) 5 int8_pos(UNUSED) 6 fp16_pos(i32) 7 block_idx(UNUSED)
// ws: W fp16 (90.2 MB) | x16 (512 KB) | cum64 (2.82 MB)
// ---------------------------------------------------------------------------
extern "C" void kernel_launch(void* const* d_in, const int* in_sizes, int n_in,
                              void* d_out, int out_size, void* d_ws,
                              size_t ws_size, hipStream_t stream) {
  const float* x      = (const float*)d_in[0];
  const int*   i8     = (const int*)d_in[1];
  const float* fpdat  = (const float*)d_in[2];
  const float* scales = (const float*)d_in[3];
  const float* bias   = (const float*)d_in[4];
  const int*   fppos  = (const int*)d_in[6];

  char* wsp = (char*)d_ws;
  _Float16* W     = (_Float16*)wsp;
  _Float16* x16   = (_Float16*)(wsp + (size_t)NUMEL * sizeof(_Float16));
  int*      cum64 = (int*)(wsp + (size_t)NUMEL * sizeof(_Float16)
                               + (size_t)TOK * INF * sizeof(_Float16));
  float*    out   = (float*)d_out;

  const int n8 = in_sizes[1];
  const int nf = in_sizes[2];

  hipMemsetAsync(out, 0, (size_t)out_size * sizeof(float), stream);
  precompute_kernel<<<(NSLC + 256) / 256 + 1, 256, 0, stream>>>(x, fppos, nf,
                                                                x16, cum64);
  dequant_kernel<<<NUMEL / (8 * 256), 256, 0, stream>>>(i8, fpdat, fppos,
                                                        scales, cum64, W, n8);
  gemm_kernel<<<NBLK * KSPL, 256, 0, stream>>>(x16, W, bias, out);
}